// Round 1
// baseline (38337.958 us; speedup 1.0000x reference)
//
#include <hip/hip_runtime.h>

typedef unsigned short ushort;
typedef unsigned int uint32;
typedef __attribute__((ext_vector_type(8))) short bf16x8;
typedef __attribute__((ext_vector_type(4))) float f32x4;

#define BATCH 16
#define TT 2048
#define HID 256

__device__ __forceinline__ ushort f2bf(float f) {
  union { float f; uint32 u; } v; v.f = f;
  uint32 r = v.u + 0x7FFFu + ((v.u >> 16) & 1u);
  return (ushort)(r >> 16);
}
__device__ __forceinline__ float bf2f(ushort u) {
  union { uint32 u; float f; } v; v.u = ((uint32)u) << 16; return v.f;
}
__device__ __forceinline__ float sigm(float x) { return 1.0f / (1.0f + __expf(-x)); }
__device__ __forceinline__ float tanh_fast(float x) { return 1.0f - 2.0f / (__expf(2.0f * x) + 1.0f); }

// ---------------- prep: casts + weight concat + bias sums ----------------
__global__ void prep_kernel(
    const float* __restrict__ x,
    const float* __restrict__ dWih_f, const float* __restrict__ dWih_b,
    const float* __restrict__ l0Wih_f, const float* __restrict__ l0Wih_b,
    const float* __restrict__ l1Wih_f, const float* __restrict__ l1Wih_b,
    const float* __restrict__ dbih_f, const float* __restrict__ dbhh_f,
    const float* __restrict__ dbih_b, const float* __restrict__ dbhh_b,
    const float* __restrict__ l0bih_f, const float* __restrict__ l0bhh_f,
    const float* __restrict__ l0bih_b, const float* __restrict__ l0bhh_b,
    const float* __restrict__ l1bih_f, const float* __restrict__ l1bhh_f,
    const float* __restrict__ l1bih_b, const float* __restrict__ l1bhh_b,
    ushort* __restrict__ xbf, ushort* __restrict__ wA, ushort* __restrict__ wB,
    ushort* __restrict__ wC, float* __restrict__ biasA, float* __restrict__ biasB,
    float* __restrict__ biasC)
{
  int g = blockIdx.x * blockDim.x + threadIdx.x;
  int str = gridDim.x * blockDim.x;
  for (int i = g; i < (BATCH * TT * 256) / 4; i += str) {
    float4 v = ((const float4*)x)[i];
    ushort4 o; o.x = f2bf(v.x); o.y = f2bf(v.y); o.z = f2bf(v.z); o.w = f2bf(v.w);
    ((ushort4*)xbf)[i] = o;
  }
  for (int i = g; i < 2048 * 256; i += str)
    wA[i] = f2bf(i < 1024 * 256 ? dWih_f[i] : dWih_b[i - 1024 * 256]);
  for (int i = g; i < 2048 * 256; i += str)
    wB[i] = f2bf(i < 1024 * 256 ? l0Wih_f[i] : l0Wih_b[i - 1024 * 256]);
  for (int i = g; i < 2048 * 512; i += str)
    wC[i] = f2bf(i < 1024 * 512 ? l1Wih_f[i] : l1Wih_b[i - 1024 * 512]);
  for (int i = g; i < 2048; i += str) {
    biasA[i] = i < 1024 ? dbih_f[i] + dbhh_f[i] : dbih_b[i - 1024] + dbhh_b[i - 1024];
    biasB[i] = i < 1024 ? l0bih_f[i] + l0bhh_f[i] : l0bih_b[i - 1024] + l0bhh_b[i - 1024];
    biasC[i] = i < 1024 ? l1bih_f[i] + l1bhh_f[i] : l1bih_b[i - 1024] + l1bhh_b[i - 1024];
  }
}

// ---------------- GEMM: xp = A[32768,K] * B[2048,K]^T + bias, out bf16 ----------------
// 128x128 tile, BK=64, 4 waves 2x2, reg-staged LDS with T2 XOR swizzle.
__global__ __launch_bounds__(256) void gemm_xp(
    const ushort* __restrict__ A, const ushort* __restrict__ B, int K,
    const float* __restrict__ bias, ushort* __restrict__ xp)
{
  __shared__ __align__(16) ushort lA[128 * 64];
  __shared__ __align__(16) ushort lB[128 * 64];
  const int tid = threadIdx.x;
  const int lane = tid & 63, wv = tid >> 6;
  const int lo = lane & 15, hi = lane >> 4;
  const int wr = wv >> 1, wc = wv & 1;
  const int bm = blockIdx.y * 128, bn = blockIdx.x * 128;

  f32x4 acc[4][4] = {};

  const int nk = K >> 6;
  for (int kt = 0; kt < nk; ++kt) {
    uint4 ra[4], rb[4];
#pragma unroll
    for (int i = 0; i < 4; ++i) {
      int slot = i * 256 + tid;
      int r = slot >> 3, c8 = slot & 7;
      ra[i] = *(const uint4*)(A + (size_t)(bm + r) * K + kt * 64 + c8 * 8);
      rb[i] = *(const uint4*)(B + (size_t)(bn + r) * K + kt * 64 + c8 * 8);
    }
    __syncthreads();
#pragma unroll
    for (int i = 0; i < 4; ++i) {
      int slot = i * 256 + tid;
      int r = slot >> 3, c8 = slot & 7;
      int boff = r * 128 + ((c8 ^ (r & 7)) << 4);
      *(uint4*)((char*)lA + boff) = ra[i];
      *(uint4*)((char*)lB + boff) = rb[i];
    }
    __syncthreads();
#pragma unroll
    for (int kk = 0; kk < 2; ++kk) {
      bf16x8 fa[4], fb[4];
#pragma unroll
      for (int mt = 0; mt < 4; ++mt) {
        int r = wr * 64 + mt * 16 + lo;
        int c8 = kk * 4 + hi;
        fa[mt] = *(const bf16x8*)((const char*)lA + r * 128 + ((c8 ^ (r & 7)) << 4));
      }
#pragma unroll
      for (int nt = 0; nt < 4; ++nt) {
        int r = wc * 64 + nt * 16 + lo;
        int c8 = kk * 4 + hi;
        fb[nt] = *(const bf16x8*)((const char*)lB + r * 128 + ((c8 ^ (r & 7)) << 4));
      }
#pragma unroll
      for (int mt = 0; mt < 4; ++mt)
#pragma unroll
        for (int nt = 0; nt < 4; ++nt)
          acc[mt][nt] = __builtin_amdgcn_mfma_f32_16x16x32_bf16(fa[mt], fb[nt], acc[mt][nt], 0, 0, 0);
    }
  }
  // epilogue: +bias, pack lane pairs, out col n<1024 -> dir0, else dir1
#pragma unroll
  for (int nt = 0; nt < 4; ++nt) {
    int n = bn + wc * 64 + nt * 16 + lo;
    float bv = bias[n];
#pragma unroll
    for (int mt = 0; mt < 4; ++mt) {
#pragma unroll
      for (int r = 0; r < 4; ++r) {
        float val = acc[mt][nt][r] + bv;
        uint32 h16 = f2bf(val);
        uint32 p16 = (uint32)__shfl_xor((int)h16, 1);
        if (!(lo & 1)) {
          int m = bm + wr * 64 + mt * 16 + hi * 4 + r;
          size_t dst = (size_t)(n >> 10) * ((size_t)BATCH * TT * 1024) + (size_t)m * 1024 + (n & 1023);
          *(uint32*)(xp + dst) = h16 | (p16 << 16);
        }
      }
    }
  }
}

// ---------------- sequential LSTM scan ----------------
// grid = 8 blocks: dir(2) x hidden-slice WG(4). 256 thr = 4 waves, 1 wave/SIMD.
// Weights register-resident (MFMA B-frags). h exchanged per step via agent-scope
// atomics in a double-buffered global staging buffer + release/acquire counter.
// MODE 0: dcg (produce coeff). MODE 1: layer0 (consume coeff, bf16 concat out).
// MODE 2: layer1 (consume coeff, fp32 out to d_out).
template <int MODE>
__global__ __launch_bounds__(256, 1) void scan_kernel(
    const ushort* __restrict__ xp,
    const float* __restrict__ WhhF, const float* __restrict__ WhhB,
    const float* __restrict__ cwF, const float* __restrict__ cwB,
    const float* __restrict__ cbiasF, const float* __restrict__ cbiasB,
    float* __restrict__ coefF, float* __restrict__ coefB,
    ushort* __restrict__ hstage,          // [2 dir][2 buf][16][256] bf16
    uint32* __restrict__ counters,        // [2 dir] stride 32 uints
    ushort* __restrict__ outBf, float* __restrict__ outF32)
{
  const int tid = threadIdx.x;
  const int lane = tid & 63, wv = tid >> 6;
  const int lo = lane & 15, hi = lane >> 4;
  const int dir = blockIdx.x >> 2, w = blockIdx.x & 3;

  const ushort* xpD = xp + (size_t)dir * ((size_t)BATCH * TT * 1024);
  const float* Whh = dir ? WhhB : WhhF;
  float* coefArr = dir ? coefB : coefF;
  ushort* hst = hstage + dir * (2 * BATCH * HID);
  uint32* counter = counters + dir * 32;

  const int unit = w * 64 + wv * 16 + lo;  // hidden unit this lane owns
  const int b0 = hi * 4;                   // batches b0..b0+3 via acc regs

  // static weights: W^T as B-fragments, wfrag[gate][ktile]
  bf16x8 wfrag[4][8];
#pragma unroll
  for (int gt = 0; gt < 4; ++gt) {
    const float* wrow = Whh + (size_t)(gt * HID + unit) * HID;
#pragma unroll
    for (int kt = 0; kt < 8; ++kt) {
      const float* p = wrow + kt * 32 + hi * 8;
      bf16x8 f;
#pragma unroll
      for (int j = 0; j < 8; ++j) f[j] = (short)f2bf(p[j]);
      wfrag[gt][kt] = f;
    }
  }

  float cwreg[4] = {0, 0, 0, 0};
  float cbias = 0.f;
  if (MODE == 0) {
    const float* cw = dir ? cwB : cwF;
#pragma unroll
    for (int j = 0; j < 4; ++j) cwreg[j] = cw[lane * 4 + j];
    cbias = dir ? cbiasB[0] : cbiasF[0];
  }

  float hprev[4] = {0, 0, 0, 0}, cprev[4] = {0, 0, 0, 0};
  float xg[4][4];  // [gate][r], prefetched one step ahead
  float co[4] = {0, 0, 0, 0};

  {
    const int t0 = dir ? (TT - 1) : 0;
#pragma unroll
    for (int r = 0; r < 4; ++r) {
      const ushort* p = xpD + ((size_t)(b0 + r) * TT + t0) * 1024 + unit;
#pragma unroll
      for (int gt = 0; gt < 4; ++gt) xg[gt][r] = bf2f(p[gt * HID]);
    }
  }

  for (int s = 0; s < TT; ++s) {
    if (s > 0) {
      const uint32 target = 4u * (uint32)s;
      while (__hip_atomic_load(counter, __ATOMIC_ACQUIRE, __HIP_MEMORY_SCOPE_AGENT) < target) {}
    }
    const ushort* hb = hst + (s & 1) * (BATCH * HID);

    // dcg: coeff[s-1] from full h_{s-1}; WG w handles batches 4w..4w+3, wave = 1 batch
    if (MODE == 0 && s > 0) {
      const int b = w * 4 + wv;
      const uint32* hr = (const uint32*)(hb + b * HID + lane * 4);
      uint32 u0 = __hip_atomic_load(hr + 0, __ATOMIC_RELAXED, __HIP_MEMORY_SCOPE_AGENT);
      uint32 u1 = __hip_atomic_load(hr + 1, __ATOMIC_RELAXED, __HIP_MEMORY_SCOPE_AGENT);
      float part = cwreg[0] * bf2f((ushort)u0) + cwreg[1] * bf2f((ushort)(u0 >> 16)) +
                   cwreg[2] * bf2f((ushort)u1) + cwreg[3] * bf2f((ushort)(u1 >> 16));
#pragma unroll
      for (int off = 32; off; off >>= 1) part += __shfl_xor(part, off);
      if (lane == 0) coefArr[b * TT + (s - 1)] = 0.9f * sigm(part + cbias);
    }

    // A-frags of h_{s-1}: agent-scope dword loads (bypass stale per-XCD L2)
    bf16x8 af[8];
#pragma unroll
    for (int kt = 0; kt < 8; ++kt) {
      const uint32* p = (const uint32*)(hb + lo * HID + kt * 32 + hi * 8);
      union { bf16x8 v; uint32 u[4]; } tmp;
#pragma unroll
      for (int q = 0; q < 4; ++q)
        tmp.u[q] = __hip_atomic_load(p + q, __ATOMIC_RELAXED, __HIP_MEMORY_SCOPE_AGENT);
      af[kt] = tmp.v;
    }

    f32x4 acc[4] = {};
#pragma unroll
    for (int kt = 0; kt < 8; ++kt)
#pragma unroll
      for (int gt = 0; gt < 4; ++gt)
        acc[gt] = __builtin_amdgcn_mfma_f32_16x16x32_bf16(af[kt], wfrag[gt][kt], acc[gt], 0, 0, 0);

#pragma unroll
    for (int r = 0; r < 4; ++r) {
      float gi = acc[0][r] + xg[0][r];
      float gf = acc[1][r] + xg[1][r];
      float gg = acc[2][r] + xg[2][r];
      float go = acc[3][r] + xg[3][r];
      float cn = sigm(gf) * cprev[r] + sigm(gi) * tanh_fast(gg);
      float hn = sigm(go) * tanh_fast(cn) + co[r] * hprev[r];
      cprev[r] = cn; hprev[r] = hn;
    }

    // post h slice: pack lane pairs -> agent-scope uint stores
    {
      ushort* ho = hst + ((s + 1) & 1) * (BATCH * HID);
#pragma unroll
      for (int r = 0; r < 4; ++r) {
        uint32 h16 = f2bf(hprev[r]);
        uint32 p16 = (uint32)__shfl_xor((int)h16, 1);
        if (!(lo & 1))
          __hip_atomic_store((uint32*)(ho + (b0 + r) * HID + unit), h16 | (p16 << 16),
                             __ATOMIC_RELAXED, __HIP_MEMORY_SCOPE_AGENT);
      }
    }
    __syncthreads();
    if (tid == 0)
      __hip_atomic_fetch_add(counter, 1u, __ATOMIC_RELEASE, __HIP_MEMORY_SCOPE_AGENT);

    // outputs (off the sync critical path)
    const int t_nat = dir ? (TT - 1 - s) : s;
    if (MODE == 1) {
#pragma unroll
      for (int r = 0; r < 4; ++r)
        outBf[((size_t)(b0 + r) * TT + t_nat) * 512 + dir * 256 + unit] = f2bf(hprev[r]);
    } else if (MODE == 2) {
#pragma unroll
      for (int r = 0; r < 4; ++r)
        outF32[((size_t)(b0 + r) * TT + t_nat) * 512 + dir * 256 + unit] = hprev[r];
    }

    // prefetch xg (and coeff) for step s+1
    if (s + 1 < TT) {
      const int tn = dir ? (TT - 2 - s) : (s + 1);
#pragma unroll
      for (int r = 0; r < 4; ++r) {
        const ushort* p = xpD + ((size_t)(b0 + r) * TT + tn) * 1024 + unit;
#pragma unroll
        for (int gt = 0; gt < 4; ++gt) xg[gt][r] = bf2f(p[gt * HID]);
        if (MODE != 0) co[r] = coefArr[(b0 + r) * TT + (s + 1)];
      }
    }
  }

  // final coeff for s = TT-1 (dcg)
  if (MODE == 0) {
    while (__hip_atomic_load(counter, __ATOMIC_ACQUIRE, __HIP_MEMORY_SCOPE_AGENT) < 4u * (uint32)TT) {}
    const ushort* hb = hst;  // buf (TT & 1) == 0 holds h_{TT-1}
    const int b = w * 4 + wv;
    const uint32* hr = (const uint32*)(hb + b * HID + lane * 4);
    uint32 u0 = __hip_atomic_load(hr + 0, __ATOMIC_RELAXED, __HIP_MEMORY_SCOPE_AGENT);
    uint32 u1 = __hip_atomic_load(hr + 1, __ATOMIC_RELAXED, __HIP_MEMORY_SCOPE_AGENT);
    float part = cwreg[0] * bf2f((ushort)u0) + cwreg[1] * bf2f((ushort)(u0 >> 16)) +
                 cwreg[2] * bf2f((ushort)u1) + cwreg[3] * bf2f((ushort)(u1 >> 16));
#pragma unroll
    for (int off = 32; off; off >>= 1) part += __shfl_xor(part, off);
    if (lane == 0) coefArr[b * TT + (TT - 1)] = 0.9f * sigm(part + cbias);
  }
}

extern "C" void kernel_launch(void* const* d_in, const int* in_sizes, int n_in,
                              void* d_out, int out_size, void* d_ws, size_t ws_size,
                              hipStream_t stream)
{
  const float* x       = (const float*)d_in[0];
  const float* dWih_f  = (const float*)d_in[1];
  const float* dWhh_f  = (const float*)d_in[2];
  const float* dbih_f  = (const float*)d_in[3];
  const float* dbhh_f  = (const float*)d_in[4];
  const float* dWih_b  = (const float*)d_in[5];
  const float* dWhh_b  = (const float*)d_in[6];
  const float* dbih_b  = (const float*)d_in[7];
  const float* dbhh_b  = (const float*)d_in[8];
  const float* l0Wih_f = (const float*)d_in[9];
  const float* l0Whh_f = (const float*)d_in[10];
  const float* l0bih_f = (const float*)d_in[11];
  const float* l0bhh_f = (const float*)d_in[12];
  const float* l0Wih_b = (const float*)d_in[13];
  const float* l0Whh_b = (const float*)d_in[14];
  const float* l0bih_b = (const float*)d_in[15];
  const float* l0bhh_b = (const float*)d_in[16];
  const float* l1Wih_f = (const float*)d_in[17];
  const float* l1Whh_f = (const float*)d_in[18];
  const float* l1bih_f = (const float*)d_in[19];
  const float* l1bhh_f = (const float*)d_in[20];
  const float* l1Wih_b = (const float*)d_in[21];
  const float* l1Whh_b = (const float*)d_in[22];
  const float* l1bih_b = (const float*)d_in[23];
  const float* l1bhh_b = (const float*)d_in[24];
  const float* cw_f    = (const float*)d_in[25];
  const float* cbi_f   = (const float*)d_in[26];
  const float* cw_b    = (const float*)d_in[27];
  const float* cbi_b   = (const float*)d_in[28];

  char* ws = (char*)d_ws;
  constexpr size_t OFF_XP   = 0;
  constexpr size_t SZ_XP    = 2ull * BATCH * TT * 1024 * 2;   // 128 MB
  constexpr size_t OFF_XCAT = OFF_XP + SZ_XP;
  constexpr size_t SZ_XCAT  = (size_t)BATCH * TT * 512 * 2;   // 32 MB
  constexpr size_t OFF_XBF  = OFF_XCAT + SZ_XCAT;
  constexpr size_t SZ_XBF   = (size_t)BATCH * TT * 256 * 2;   // 16 MB
  constexpr size_t OFF_WA   = OFF_XBF + SZ_XBF;
  constexpr size_t SZ_WAB   = 2048ull * 256 * 2;
  constexpr size_t OFF_WB   = OFF_WA + SZ_WAB;
  constexpr size_t OFF_WC   = OFF_WB + SZ_WAB;
  constexpr size_t SZ_WC    = 2048ull * 512 * 2;
  constexpr size_t OFF_BA   = OFF_WC + SZ_WC;
  constexpr size_t OFF_BB   = OFF_BA + 8192;
  constexpr size_t OFF_BC   = OFF_BB + 8192;
  constexpr size_t OFF_CF   = OFF_BC + 8192;
  constexpr size_t SZ_CO    = (size_t)BATCH * TT * 4;
  constexpr size_t OFF_CB   = OFF_CF + SZ_CO;
  constexpr size_t OFF_SYNC = OFF_CB + SZ_CO;
  constexpr size_t SZ_HST   = 3ull * 2 * 2 * BATCH * HID * 2; // 98304
  constexpr size_t SZ_CNT   = 3ull * 2 * 32 * 4;              // 768
  constexpr size_t NEED     = OFF_SYNC + SZ_HST + SZ_CNT;
  if (ws_size < NEED) return;  // cannot run safely

  ushort* xp    = (ushort*)(ws + OFF_XP);
  ushort* xcat  = (ushort*)(ws + OFF_XCAT);
  ushort* xbf   = (ushort*)(ws + OFF_XBF);
  ushort* wA    = (ushort*)(ws + OFF_WA);
  ushort* wB    = (ushort*)(ws + OFF_WB);
  ushort* wC    = (ushort*)(ws + OFF_WC);
  float*  biasA = (float*)(ws + OFF_BA);
  float*  biasB = (float*)(ws + OFF_BB);
  float*  biasC = (float*)(ws + OFF_BC);
  float*  cf    = (float*)(ws + OFF_CF);
  float*  cb    = (float*)(ws + OFF_CB);
  ushort* hst   = (ushort*)(ws + OFF_SYNC);
  uint32* cnt   = (uint32*)(ws + OFF_SYNC + SZ_HST);

  prep_kernel<<<512, 256, 0, stream>>>(
      x, dWih_f, dWih_b, l0Wih_f, l0Wih_b, l1Wih_f, l1Wih_b,
      dbih_f, dbhh_f, dbih_b, dbhh_b, l0bih_f, l0bhh_f, l0bih_b, l0bhh_b,
      l1bih_f, l1bhh_f, l1bih_b, l1bhh_b,
      xbf, wA, wB, wC, biasA, biasB, biasC);
  hipMemsetAsync(ws + OFF_SYNC, 0, SZ_HST + SZ_CNT, stream);

  // phase A: dcg
  gemm_xp<<<dim3(16, 256), 256, 0, stream>>>(xbf, wA, 256, biasA, xp);
  scan_kernel<0><<<8, 256, 0, stream>>>(xp, dWhh_f, dWhh_b, cw_f, cw_b, cbi_f, cbi_b,
                                        cf, cb, hst + 0 * (2 * 2 * BATCH * HID), cnt + 0 * 64,
                                        (ushort*)nullptr, (float*)nullptr);
  // phase B: layer 0
  gemm_xp<<<dim3(16, 256), 256, 0, stream>>>(xbf, wB, 256, biasB, xp);
  scan_kernel<1><<<8, 256, 0, stream>>>(xp, l0Whh_f, l0Whh_b, cw_f, cw_b, cbi_f, cbi_b,
                                        cf, cb, hst + 1 * (2 * 2 * BATCH * HID), cnt + 1 * 64,
                                        xcat, (float*)nullptr);
  // phase C: layer 1
  gemm_xp<<<dim3(16, 256), 256, 0, stream>>>(xcat, wC, 512, biasC, xp);
  scan_kernel<2><<<8, 256, 0, stream>>>(xp, l1Whh_f, l1Whh_b, cw_f, cw_b, cbi_f, cbi_b,
                                        cf, cb, hst + 2 * (2 * 2 * BATCH * HID), cnt + 2 * 64,
                                        (ushort*)nullptr, (float*)d_out);
}